// Round 1
// baseline (2142.754 us; speedup 1.0000x reference)
//
#include <hip/hip_runtime.h>

// ---------------------------------------------------------------------------
// Transformer forward, MI355X gfx950. bf16 MFMA compute, fp32 accum/output.
// Layout conventions:
//   activations: row = b*S + s (M = 2048 rows)
//   kqv buffer:  [2048][3072] bf16, cols = [k1(h,k) | q1(h,k) | v(h,d)]
//   k/q buffers: [2048][1024] bf16 (post 2nd MLP layer)
// ---------------------------------------------------------------------------

typedef __attribute__((ext_vector_type(8))) short bf16x8;
typedef __attribute__((ext_vector_type(4))) float f32x4;

#define L_ 8
#define S_ 1024
#define E_ 1024
#define B_ 2
#define H_ 16
#define V_ 32000
#define M_ 2048  // B*S

__device__ __forceinline__ unsigned short f2b(float f) {
  union { float f; unsigned int u; } v; v.f = f;
  unsigned int r = v.u + 0x7FFFu + ((v.u >> 16) & 1u);
  return (unsigned short)(r >> 16);
}

// ---------------- weight conversion kernels ----------------
__global__ void cvt_kernel(const float* __restrict__ src, unsigned short* __restrict__ dst) {
  size_t i = ((size_t)blockIdx.x * 256 + threadIdx.x) * 4;
  float4 v = *(const float4*)(src + i);
  unsigned short* d = dst + i;
  d[0] = f2b(v.x); d[1] = f2b(v.y); d[2] = f2b(v.z); d[3] = f2b(v.w);
}

// interleave per-layer [perLayer] fp32 chunks into dst with stride dstStride
__global__ void cvt_seg_kernel(const float* __restrict__ src, unsigned short* __restrict__ dst,
                               int perLayer, int dstStride, int dstOff) {
  size_t i = ((size_t)blockIdx.x * 256 + threadIdx.x) * 4;
  int l = (int)(i / perLayer);
  int off = (int)(i - (size_t)l * perLayer);
  float4 v = *(const float4*)(src + i);
  unsigned short* d = dst + (size_t)l * dstStride + dstOff + off;
  d[0] = f2b(v.x); d[1] = f2b(v.y); d[2] = f2b(v.z); d[3] = f2b(v.w);
}

__global__ void biascat_kernel(const float* __restrict__ k1b, const float* __restrict__ q1b,
                               const float* __restrict__ vb, float* __restrict__ bcat) {
  int i = blockIdx.x * 256 + threadIdx.x;  // 8*3072 exact
  int l = i / 3072, j = i - l * 3072;
  float v;
  if (j < 1024)      v = k1b[l * 1024 + j];
  else if (j < 2048) v = q1b[l * 1024 + j - 1024];
  else               v = vb [l * 1024 + j - 2048];
  bcat[i] = v;
}

// ---------------- embedding ----------------
__global__ void embed_kernel(const int* __restrict__ tokens, const float* __restrict__ emb,
                             const float* __restrict__ pe, float* __restrict__ x32,
                             unsigned short* __restrict__ xb) {
  int row = blockIdx.x;           // b*S + s
  int s = row & (S_ - 1);
  int e0 = threadIdx.x * 4;
  int tok = tokens[row];
  float4 ev = *(const float4*)(emb + (size_t)tok * E_ + e0);
  float4 pv = *(const float4*)(pe + (size_t)s * E_ + e0);
  float4 v; v.x = ev.x + pv.x; v.y = ev.y + pv.y; v.z = ev.z + pv.z; v.w = ev.w + pv.w;
  *(float4*)(x32 + (size_t)row * E_ + e0) = v;
  ushort4 o; o.x = f2b(v.x); o.y = f2b(v.y); o.z = f2b(v.z); o.w = f2b(v.w);
  *(ushort4*)(xb + (size_t)row * E_ + e0) = o;
}

// ---------------- generic C = relu(A * W^T + bias) GEMM ----------------
// A: [M][K] bf16 row-major, W: [N][K] bf16 row-major. BN = 128 fixed, BK = 32.
// RELU: 0 none, 1 all, 2 only cols < reluN.
template <int BM, int RELU, int OBF, int OF32>
__global__ __launch_bounds__(256) void gemm_bt(
    const unsigned short* __restrict__ A, const unsigned short* __restrict__ W,
    const float* __restrict__ bias, unsigned short* __restrict__ Cb,
    float* __restrict__ Cf, int K, int N, int reluN) {
  constexpr int ACH = (BM * 4) / 256;  // A 16B-chunks per thread per k-step
  constexpr int FM = BM / 32;          // 16x16 frags per wave (M dir)
  __shared__ __align__(16) unsigned short sA[BM * 32];
  __shared__ __align__(16) unsigned short sB[128 * 32];
  const int tid = threadIdx.x;
  const int lane = tid & 63, wave = tid >> 6;
  const int l16 = lane & 15, lhi = lane >> 4;
  const int row0 = blockIdx.x * BM, col0 = blockIdx.y * 128;
  const int wm = (wave >> 1) * (BM / 2), wn = (wave & 1) * 64;

  f32x4 acc[FM][4] = {};
  uint4 ra[ACH], rb[2];

#pragma unroll
  for (int r = 0; r < ACH; r++) {
    int c = r * 256 + tid;
    ra[r] = *(const uint4*)(A + (size_t)(row0 + (c >> 2)) * K + ((c & 3) << 3));
  }
#pragma unroll
  for (int r = 0; r < 2; r++) {
    int c = r * 256 + tid;
    rb[r] = *(const uint4*)(W + (size_t)(col0 + (c >> 2)) * K + ((c & 3) << 3));
  }

  for (int k0 = 0; k0 < K; k0 += 32) {
    __syncthreads();
#pragma unroll
    for (int r = 0; r < ACH; r++) { int c = r * 256 + tid; *(uint4*)(sA + c * 8) = ra[r]; }
#pragma unroll
    for (int r = 0; r < 2; r++) { int c = r * 256 + tid; *(uint4*)(sB + c * 8) = rb[r]; }
    __syncthreads();
    if (k0 + 32 < K) {
#pragma unroll
      for (int r = 0; r < ACH; r++) {
        int c = r * 256 + tid;
        ra[r] = *(const uint4*)(A + (size_t)(row0 + (c >> 2)) * K + k0 + 32 + ((c & 3) << 3));
      }
#pragma unroll
      for (int r = 0; r < 2; r++) {
        int c = r * 256 + tid;
        rb[r] = *(const uint4*)(W + (size_t)(col0 + (c >> 2)) * K + k0 + 32 + ((c & 3) << 3));
      }
    }
    bf16x8 af[FM], bfr[4];
#pragma unroll
    for (int i = 0; i < FM; i++)
      af[i] = *(const bf16x8*)(sA + (wm + i * 16 + l16) * 32 + (lhi << 3));
#pragma unroll
    for (int j = 0; j < 4; j++)
      bfr[j] = *(const bf16x8*)(sB + (wn + j * 16 + l16) * 32 + (lhi << 3));
#pragma unroll
    for (int i = 0; i < FM; i++)
#pragma unroll
      for (int j = 0; j < 4; j++)
        acc[i][j] = __builtin_amdgcn_mfma_f32_16x16x32_bf16(af[i], bfr[j], acc[i][j], 0, 0, 0);
  }

#pragma unroll
  for (int j = 0; j < 4; j++) {
    const int col = col0 + wn + j * 16 + l16;
    const float bv = bias[col];
    const bool dorelu = (RELU == 1) || (RELU == 2 && col < reluN);
#pragma unroll
    for (int i = 0; i < FM; i++) {
#pragma unroll
      for (int r = 0; r < 4; r++) {
        const int row = row0 + wm + i * 16 + (lhi << 2) + r;
        float v = acc[i][j][r] + bv;
        if (dorelu) v = fmaxf(v, 0.f);
        if (OBF) Cb[(size_t)row * N + col] = f2b(v);
        if (OF32) Cf[(size_t)row * N + col] = v;
      }
    }
  }
}

// ---------------- per-head K2/Q2: out = relu(A_h * W_h^T + b_h) ----------------
// A_h: rows of kqv (stride 3072) at col (which?1024:0)+h*64;  W_h: [64][64].
__global__ __launch_bounds__(256) void k2q2_kernel(
    const unsigned short* __restrict__ kqv, const unsigned short* __restrict__ wk2,
    const unsigned short* __restrict__ wq2, const float* __restrict__ k2b,
    const float* __restrict__ q2b, unsigned short* __restrict__ kbuf,
    unsigned short* __restrict__ qbuf) {
  const int m0 = blockIdx.x * 64;
  const int h = blockIdx.y;
  const int which = blockIdx.z;
  const unsigned short* Ap = kqv + (which ? 1024 : 0) + h * 64;
  const unsigned short* Wp = (which ? wq2 : wk2) + h * 4096;
  const float* bias = (which ? q2b : k2b) + h * 64;
  unsigned short* out = (which ? qbuf : kbuf) + h * 64;
  const int lane = threadIdx.x & 63, wave = threadIdx.x >> 6;
  const int l16 = lane & 15, lhi = lane >> 4;
  const int mw = m0 + wave * 16;

  f32x4 acc[4] = {};
#pragma unroll
  for (int ks = 0; ks < 2; ks++) {
    bf16x8 a = *(const bf16x8*)(Ap + (size_t)(mw + l16) * 3072 + ks * 32 + (lhi << 3));
#pragma unroll
    for (int j = 0; j < 4; j++) {
      bf16x8 b = *(const bf16x8*)(Wp + (j * 16 + l16) * 64 + ks * 32 + (lhi << 3));
      acc[j] = __builtin_amdgcn_mfma_f32_16x16x32_bf16(a, b, acc[j], 0, 0, 0);
    }
  }
#pragma unroll
  for (int j = 0; j < 4; j++) {
    float bv = bias[j * 16 + l16];
#pragma unroll
    for (int r = 0; r < 4; r++) {
      int row = mw + (lhi << 2) + r;
      float v = fmaxf(acc[j][r] + bv, 0.f);
      out[(size_t)row * 1024 + j * 16 + l16] = f2b(v);
    }
  }
}

// ---------------- fused attention (future-masked, online softmax) ----------------
// grid: (S/64, H, B). block: 256 (4 waves, 16 q-rows each).
__global__ __launch_bounds__(256) void attn_kernel(
    const unsigned short* __restrict__ qbuf,  // [2048][1024]
    const unsigned short* __restrict__ kbuf,  // [2048][1024]
    const unsigned short* __restrict__ kqv,   // v at col 2048, stride 3072
    float* __restrict__ o32) {                // [2048][1024]
  constexpr int LD = 72;  // padded row (bf16 elems) -> 144B stride, 16B aligned
  __shared__ __align__(16) unsigned short sK[64 * LD];
  __shared__ __align__(16) unsigned short sV[64 * LD];  // transposed: [d][t]
  __shared__ __align__(16) unsigned short sP[4 * 16 * LD];
  const int bx = blockIdx.x, h = blockIdx.y, b = blockIdx.z;
  const int tid = threadIdx.x, lane = tid & 63, wave = tid >> 6;
  const int l16 = lane & 15, lhi = lane >> 4;
  const int base = b * S_;

  // Q fragments (held in registers for whole kernel)
  const int qrow = bx * 64 + wave * 16 + l16;
  bf16x8 aq[2];
#pragma unroll
  for (int ks = 0; ks < 2; ks++)
    aq[ks] = *(const bf16x8*)(qbuf + (size_t)(base + qrow) * 1024 + h * 64 + ks * 32 + (lhi << 3));

  f32x4 oacc[4] = {};
  float mrun[4], lrun[4];
#pragma unroll
  for (int r = 0; r < 4; r++) { mrun[r] = -1e10f; lrun[r] = 0.f; }
  const int srow_base = bx * 64 + wave * 16 + (lhi << 2);

  for (int t0 = 0; t0 < S_; t0 += 64) {
    uint4 rk[2], rv[2];
#pragma unroll
    for (int r = 0; r < 2; r++) {
      int c = r * 256 + tid;
      int trow = c >> 3, c8 = (c & 7) << 3;
      rk[r] = *(const uint4*)(kbuf + (size_t)(base + t0 + trow) * 1024 + h * 64 + c8);
      rv[r] = *(const uint4*)(kqv + (size_t)(base + t0 + trow) * 3072 + 2048 + h * 64 + c8);
    }
    __syncthreads();  // prior iteration's LDS reads done
#pragma unroll
    for (int r = 0; r < 2; r++) {
      int c = r * 256 + tid;
      int trow = c >> 3, c8 = (c & 7) << 3;
      *(uint4*)(sK + trow * LD + c8) = rk[r];
      const unsigned short* ts = (const unsigned short*)&rv[r];
#pragma unroll
      for (int j = 0; j < 8; j++) sV[(c8 + j) * LD + trow] = ts[j];
    }
    __syncthreads();

    // S = Q K^T
    f32x4 sacc[4] = {};
#pragma unroll
    for (int ks = 0; ks < 2; ks++) {
#pragma unroll
      for (int nt = 0; nt < 4; nt++) {
        bf16x8 bk = *(const bf16x8*)(sK + (nt * 16 + l16) * LD + ks * 32 + (lhi << 3));
        sacc[nt] = __builtin_amdgcn_mfma_f32_16x16x32_bf16(aq[ks], bk, sacc[nt], 0, 0, 0);
      }
    }
    // scale + future-mask (t <= s masked to exactly -1e10, matching fp32 absorption)
    float p[4][4];
#pragma unroll
    for (int nt = 0; nt < 4; nt++) {
      int tcol = t0 + nt * 16 + l16;
#pragma unroll
      for (int r = 0; r < 4; r++) {
        float v = sacc[nt][r] * 0.125f;
        if (tcol <= srow_base + r) v = -1e10f;
        p[nt][r] = v;
      }
    }
    // online softmax per row r
#pragma unroll
    for (int r = 0; r < 4; r++) {
      float m = fmaxf(fmaxf(p[0][r], p[1][r]), fmaxf(p[2][r], p[3][r]));
#pragma unroll
      for (int off = 1; off < 16; off <<= 1) m = fmaxf(m, __shfl_xor(m, off, 16));
      float mnew = fmaxf(mrun[r], m);
      float alpha = __expf(mrun[r] - mnew);
      mrun[r] = mnew;
      float rs = 0.f;
#pragma unroll
      for (int nt = 0; nt < 4; nt++) {
        float e = __expf(p[nt][r] - mnew);
        p[nt][r] = e; rs += e;
      }
#pragma unroll
      for (int off = 1; off < 16; off <<= 1) rs += __shfl_xor(rs, off, 16);
      lrun[r] = lrun[r] * alpha + rs;
      oacc[0][r] *= alpha; oacc[1][r] *= alpha; oacc[2][r] *= alpha; oacc[3][r] *= alpha;
    }
    // P -> LDS (C-layout to A-layout transpose)
    unsigned short* sPw = sP + wave * 16 * LD;
#pragma unroll
    for (int nt = 0; nt < 4; nt++)
#pragma unroll
      for (int r = 0; r < 4; r++)
        sPw[((lhi << 2) + r) * LD + nt * 16 + l16] = f2b(p[nt][r]);
    // O += P V   (same-wave LDS write->read; compiler inserts lgkmcnt)
#pragma unroll
    for (int ks = 0; ks < 2; ks++) {
      bf16x8 ap = *(const bf16x8*)(sPw + l16 * LD + ks * 32 + (lhi << 3));
#pragma unroll
      for (int nt = 0; nt < 4; nt++) {
        bf16x8 bv = *(const bf16x8*)(sV + (nt * 16 + l16) * LD + ks * 32 + (lhi << 3));
        oacc[nt] = __builtin_amdgcn_mfma_f32_16x16x32_bf16(ap, bv, oacc[nt], 0, 0, 0);
      }
    }
  }
#pragma unroll
  for (int nt = 0; nt < 4; nt++) {
#pragma unroll
    for (int r = 0; r < 4; r++) {
      int row = srow_base + r;
      o32[(size_t)(base + row) * 1024 + h * 64 + nt * 16 + l16] = oacc[nt][r] / lrun[r];
    }
  }
}

// ---------------- residual + LayerNorm -> bf16 ----------------
__global__ __launch_bounds__(256) void ln_kernel(
    const float* __restrict__ x32, const float* __restrict__ o32,
    const float* __restrict__ lnw, const float* __restrict__ lnb,
    unsigned short* __restrict__ yn) {
  __shared__ float red[8];
  const int row = blockIdx.x, tid = threadIdx.x;
  const int lane = tid & 63, wave = tid >> 6;
  const int e0 = tid * 4;
  float4 xv = *(const float4*)(x32 + (size_t)row * E_ + e0);
  float4 ov = *(const float4*)(o32 + (size_t)row * E_ + e0);
  float y0 = xv.x + ov.x, y1 = xv.y + ov.y, y2 = xv.z + ov.z, y3 = xv.w + ov.w;
  float s = y0 + y1 + y2 + y3;
  float sq = y0 * y0 + y1 * y1 + y2 * y2 + y3 * y3;
#pragma unroll
  for (int off = 32; off > 0; off >>= 1) {
    s += __shfl_xor(s, off, 64);
    sq += __shfl_xor(sq, off, 64);
  }
  if (lane == 0) { red[wave * 2] = s; red[wave * 2 + 1] = sq; }
  __syncthreads();
  float ts = red[0] + red[2] + red[4] + red[6];
  float tsq = red[1] + red[3] + red[5] + red[7];
  float mu = ts * (1.f / E_);
  float var = tsq * (1.f / E_) - mu * mu;
  float rstd = rsqrtf(var + 1e-5f);
  float4 gv = *(const float4*)(lnw + e0);
  float4 bv = *(const float4*)(lnb + e0);
  ushort4 o;
  o.x = f2b((y0 - mu) * rstd * gv.x + bv.x);
  o.y = f2b((y1 - mu) * rstd * gv.y + bv.y);
  o.z = f2b((y2 - mu) * rstd * gv.z + bv.z);
  o.w = f2b((y3 - mu) * rstd * gv.w + bv.w);
  *(ushort4*)(yn + (size_t)row * E_ + e0) = o;
}

// ---------------------------------------------------------------------------
extern "C" void kernel_launch(void* const* d_in, const int* in_sizes, int n_in,
                              void* d_out, int out_size, void* d_ws, size_t ws_size,
                              hipStream_t stream) {
  const int* tokens  = (const int*)d_in[0];
  const float* emb   = (const float*)d_in[1];
  const float* pe    = (const float*)d_in[2];
  const float* k1w   = (const float*)d_in[3];
  const float* k1b   = (const float*)d_in[4];
  const float* k2w   = (const float*)d_in[5];
  const float* k2b   = (const float*)d_in[6];
  const float* q1w   = (const float*)d_in[7];
  const float* q1b   = (const float*)d_in[8];
  const float* q2w   = (const float*)d_in[9];
  const float* q2b   = (const float*)d_in[10];
  const float* vw    = (const float*)d_in[11];
  const float* vb    = (const float*)d_in[12];
  const float* lnw   = (const float*)d_in[13];
  const float* lnb   = (const float*)d_in[14];
  const float* p1w   = (const float*)d_in[15];
  const float* p1b   = (const float*)d_in[16];
  const float* p2w   = (const float*)d_in[17];
  const float* p2b   = (const float*)d_in[18];
  const float* predw = (const float*)d_in[19];
  const float* predb = (const float*)d_in[20];
  float* out = (float*)d_out;

  // -------- workspace carve --------
  char* p = (char*)d_ws;
  auto alloc = [&](size_t bytes) -> char* {
    char* r = p; p += (bytes + 255) & ~(size_t)255; return r;
  };
  unsigned short* wcat  = (unsigned short*)alloc((size_t)L_ * 3072 * 1024 * 2);  // k1|q1|v weights
  unsigned short* wk2   = (unsigned short*)alloc((size_t)L_ * H_ * 64 * 64 * 2);
  unsigned short* wq2   = (unsigned short*)alloc((size_t)L_ * H_ * 64 * 64 * 2);
  unsigned short* wp1   = (unsigned short*)alloc((size_t)L_ * 1024 * 1024 * 2);
  unsigned short* wp2   = (unsigned short*)alloc((size_t)L_ * 1024 * 1024 * 2);
  unsigned short* wpred = (unsigned short*)alloc((size_t)V_ * 1024 * 2);
  float*          bcat  = (float*)alloc((size_t)L_ * 3072 * 4);
  float*          x32   = (float*)alloc((size_t)M_ * 1024 * 4);
  unsigned short* xb    = (unsigned short*)alloc((size_t)M_ * 1024 * 2);
  unsigned short* kqv   = (unsigned short*)alloc((size_t)M_ * 3072 * 2);
  unsigned short* kbuf  = (unsigned short*)alloc((size_t)M_ * 1024 * 2);
  unsigned short* qbuf  = (unsigned short*)alloc((size_t)M_ * 1024 * 2);
  float*          o32   = (float*)alloc((size_t)M_ * 1024 * 4);
  unsigned short* yn    = (unsigned short*)alloc((size_t)M_ * 1024 * 2);
  unsigned short* h1    = (unsigned short*)alloc((size_t)M_ * 1024 * 2);
  if ((size_t)(p - (char*)d_ws) > ws_size) return;  // not enough scratch: bail (no corruption)

  // -------- weight conversion (fp32 -> bf16), every call (stateless) --------
  cvt_seg_kernel<<<8192, 256, 0, stream>>>(k1w, wcat, 1048576, 3145728, 0);
  cvt_seg_kernel<<<8192, 256, 0, stream>>>(q1w, wcat, 1048576, 3145728, 1048576);
  cvt_seg_kernel<<<8192, 256, 0, stream>>>(vw,  wcat, 1048576, 3145728, 2097152);
  cvt_kernel<<<512, 256, 0, stream>>>(k2w, wk2);
  cvt_kernel<<<512, 256, 0, stream>>>(q2w, wq2);
  cvt_kernel<<<8192, 256, 0, stream>>>(p1w, wp1);
  cvt_kernel<<<8192, 256, 0, stream>>>(p2w, wp2);
  cvt_kernel<<<32000, 256, 0, stream>>>(predw, wpred);
  biascat_kernel<<<96, 256, 0, stream>>>(k1b, q1b, vb, bcat);

  // -------- embedding --------
  embed_kernel<<<M_, 256, 0, stream>>>(tokens, emb, pe, x32, xb);

  // -------- layers --------
  for (int l = 0; l < L_; l++) {
    const unsigned short* wcat_l = wcat + (size_t)l * 3072 * 1024;
    const float* bcat_l = bcat + (size_t)l * 3072;
    const unsigned short* wk2_l = wk2 + (size_t)l * H_ * 64 * 64;
    const unsigned short* wq2_l = wq2 + (size_t)l * H_ * 64 * 64;
    const unsigned short* wp1_l = wp1 + (size_t)l * 1024 * 1024;
    const unsigned short* wp2_l = wp2 + (size_t)l * 1024 * 1024;

    // fused k1|q1|v projection: [2048,3072] = xb @ wcat^T ; relu on cols<2048
    gemm_bt<64, 2, 1, 0><<<dim3(32, 24), 256, 0, stream>>>(
        xb, wcat_l, bcat_l, kqv, nullptr, 1024, 3072, 2048);
    // per-head second MLP for k and q
    k2q2_kernel<<<dim3(32, 16, 2), 256, 0, stream>>>(
        kqv, wk2_l, wq2_l, k2b + l * 1024, q2b + l * 1024, kbuf, qbuf);
    // fused attention
    attn_kernel<<<dim3(16, 16, 2), 256, 0, stream>>>(qbuf, kbuf, kqv, o32);
    // residual + layernorm
    ln_kernel<<<M_, 256, 0, stream>>>(x32, o32, lnw + l * 1024, lnb + l * 1024, yn);
    // MLP
    gemm_bt<64, 1, 1, 0><<<dim3(32, 8), 256, 0, stream>>>(
        yn, wp1_l, p1b + l * 1024, h1, nullptr, 1024, 1024, 0);
    gemm_bt<64, 1, 1, 1><<<dim3(32, 8), 256, 0, stream>>>(
        h1, wp2_l, p2b + l * 1024, xb, x32, 1024, 1024, 0);
  }

  // -------- vocab projection --------
  gemm_bt<128, 0, 0, 1><<<dim3(16, 250), 256, 0, stream>>>(
      xb, wpred, predb, nullptr, out, 1024, V_, 0);
}

// Round 2
// 1554.436 us; speedup vs baseline: 1.3785x; 1.3785x over previous
//
#include <hip/hip_runtime.h>

// ---------------------------------------------------------------------------
// Transformer forward, MI355X gfx950. bf16 MFMA compute, fp32 accum/output.
//   activations: row = b*S + s (M = 2048 rows)
//   kqv buffer:  [2048][3072] bf16, cols = [k1(h,k) | q1(h,k) | v(h,d)]
// GEMMs use the m97 structure: global_load_lds width-16 staging, BK=32,
// single LDS buffer, 2 barriers/K-step, swapped-operand MFMA so each lane
// owns 4 consecutive C columns (float4 epilogue).
// ---------------------------------------------------------------------------

typedef __attribute__((ext_vector_type(8))) short bf16x8;
typedef __attribute__((ext_vector_type(4))) float f32x4;

#define L_ 8
#define S_ 1024
#define E_ 1024
#define B_ 2
#define H_ 16
#define V_ 32000
#define M_ 2048  // B*S

__device__ __forceinline__ unsigned short f2b(float f) {
  union { float f; unsigned int u; } v; v.f = f;
  unsigned int r = v.u + 0x7FFFu + ((v.u >> 16) & 1u);
  return (unsigned short)(r >> 16);
}

// global(as1) -> LDS(as3) 16-byte async copy; LDS dest = wave-uniform base + lane*16
#define GLDS16(gptr, lptr)                                                            \
  __builtin_amdgcn_global_load_lds(                                                   \
      (const __attribute__((address_space(1))) unsigned int*)(gptr),                  \
      (__attribute__((address_space(3))) unsigned int*)(lptr), 16, 0, 0)

// ---------------- weight conversion kernels ----------------
__global__ void cvt_kernel(const float* __restrict__ src, unsigned short* __restrict__ dst) {
  size_t i = ((size_t)blockIdx.x * 256 + threadIdx.x) * 4;
  float4 v = *(const float4*)(src + i);
  unsigned short* d = dst + i;
  d[0] = f2b(v.x); d[1] = f2b(v.y); d[2] = f2b(v.z); d[3] = f2b(v.w);
}

__global__ void cvt_seg_kernel(const float* __restrict__ src, unsigned short* __restrict__ dst,
                               int perLayer, int dstStride, int dstOff) {
  size_t i = ((size_t)blockIdx.x * 256 + threadIdx.x) * 4;
  int l = (int)(i / perLayer);
  int off = (int)(i - (size_t)l * perLayer);
  float4 v = *(const float4*)(src + i);
  unsigned short* d = dst + (size_t)l * dstStride + dstOff + off;
  d[0] = f2b(v.x); d[1] = f2b(v.y); d[2] = f2b(v.z); d[3] = f2b(v.w);
}

__global__ void biascat_kernel(const float* __restrict__ k1b, const float* __restrict__ q1b,
                               const float* __restrict__ vb, float* __restrict__ bcat) {
  int i = blockIdx.x * 256 + threadIdx.x;  // 8*3072 exact
  int l = i / 3072, j = i - l * 3072;
  float v;
  if (j < 1024)      v = k1b[l * 1024 + j];
  else if (j < 2048) v = q1b[l * 1024 + j - 1024];
  else               v = vb [l * 1024 + j - 2048];
  bcat[i] = v;
}

// ---------------- embedding ----------------
__global__ void embed_kernel(const int* __restrict__ tokens, const float* __restrict__ emb,
                             const float* __restrict__ pe, float* __restrict__ x32,
                             unsigned short* __restrict__ xb) {
  int row = blockIdx.x;           // b*S + s
  int s = row & (S_ - 1);
  int e0 = threadIdx.x * 4;
  int tok = tokens[row];
  float4 ev = *(const float4*)(emb + (size_t)tok * E_ + e0);
  float4 pv = *(const float4*)(pe + (size_t)s * E_ + e0);
  float4 v; v.x = ev.x + pv.x; v.y = ev.y + pv.y; v.z = ev.z + pv.z; v.w = ev.w + pv.w;
  *(float4*)(x32 + (size_t)row * E_ + e0) = v;
  ushort4 o; o.x = f2b(v.x); o.y = f2b(v.y); o.z = f2b(v.z); o.w = f2b(v.w);
  *(ushort4*)(xb + (size_t)row * E_ + e0) = o;
}

// ---------------- m97-style GEMM: C = act(A * W^T + bias) ----------------
// A: [M][K] bf16 row-major, W: [N][K] bf16 row-major. BN = 128 fixed, BK = 32.
// RELU: 0 none, 1 all, 2 only cols < reluN.
// Swapped-operand MFMA: D row-dim = W rows (C cols), D col-dim = A rows (C rows)
// -> lane (l16,lhi) reg r holds C[row0+wm+i*16+l16][col0+wn+j*16+lhi*4+r].
template <int BM, int RELU, int OBF, int OF32>
__global__ __launch_bounds__(256) void gemm97(
    const unsigned short* __restrict__ A, const unsigned short* __restrict__ W,
    const float* __restrict__ bias, unsigned short* __restrict__ Cb,
    float* __restrict__ Cf, int K, int N, int reluN) {
  constexpr int AR = BM / 64;          // A glds issues per thread per K-step
  constexpr int FM = (BM == 128) ? 4 : 2;
  constexpr int WMS = (BM == 128) ? 64 : 32;
  __shared__ __align__(16) unsigned short sA[BM * 32];
  __shared__ __align__(16) unsigned short sB[128 * 32];
  const int tid = threadIdx.x;
  const int lane = tid & 63, wave = tid >> 6;
  const int l16 = lane & 15, lhi = lane >> 4;

  // XCD-aware swizzle (all grids here are %8==0; guard anyway)
  const int gx = gridDim.x, nwg = gx * gridDim.y;
  int o = blockIdx.y * gx + blockIdx.x;
  int wg = ((nwg & 7) == 0) ? ((o & 7) * (nwg >> 3) + (o >> 3)) : o;
  const int row0 = (wg % gx) * BM, col0 = (wg / gx) * 128;

  const int wm = (wave >> 1) * WMS, wn = (wave & 1) * 64;

  // staging geometry (uniform per wave): rows covered per issue = 64
  const int srow = wave * 16 + (lane >> 2);   // within 64-row group
  const int scol = (lane & 3) * 8;            // k-offset elems

  f32x4 acc[FM][4] = {};

  for (int k0 = 0; k0 < K; k0 += 32) {
#pragma unroll
    for (int r = 0; r < AR; r++)
      GLDS16(A + (size_t)(row0 + r * 64 + srow) * K + k0 + scol,
             sA + r * 2048 + wave * 512);
#pragma unroll
    for (int r = 0; r < 2; r++)
      GLDS16(W + (size_t)(col0 + r * 64 + srow) * K + k0 + scol,
             sB + r * 2048 + wave * 512);
    __syncthreads();   // compiler emits vmcnt(0) drain before barrier

    bf16x8 af[FM], bf[4];
#pragma unroll
    for (int i = 0; i < FM; i++)
      af[i] = *(const bf16x8*)(sA + (wm + i * 16 + l16) * 32 + lhi * 8);
#pragma unroll
    for (int j = 0; j < 4; j++)
      bf[j] = *(const bf16x8*)(sB + (wn + j * 16 + l16) * 32 + lhi * 8);
#pragma unroll
    for (int i = 0; i < FM; i++)
#pragma unroll
      for (int j = 0; j < 4; j++)
        acc[i][j] = __builtin_amdgcn_mfma_f32_16x16x32_bf16(bf[j], af[i], acc[i][j], 0, 0, 0);
    __syncthreads();   // LDS reads done before next overwrite
  }

#pragma unroll
  for (int j = 0; j < 4; j++) {
    const int colb = col0 + wn + j * 16 + lhi * 4;
    const float4 bv = *(const float4*)(bias + colb);
    const bool dorelu = (RELU == 1) || (RELU == 2 && colb < reluN);
#pragma unroll
    for (int i = 0; i < FM; i++) {
      const int row = row0 + wm + i * 16 + l16;
      float v0 = acc[i][j][0] + bv.x, v1 = acc[i][j][1] + bv.y;
      float v2 = acc[i][j][2] + bv.z, v3 = acc[i][j][3] + bv.w;
      if (dorelu) {
        v0 = fmaxf(v0, 0.f); v1 = fmaxf(v1, 0.f);
        v2 = fmaxf(v2, 0.f); v3 = fmaxf(v3, 0.f);
      }
      if (OBF) {
        ushort4 ob; ob.x = f2b(v0); ob.y = f2b(v1); ob.z = f2b(v2); ob.w = f2b(v3);
        *(ushort4*)(Cb + (size_t)row * N + colb) = ob;
      }
      if (OF32) {
        float4 of; of.x = v0; of.y = v1; of.z = v2; of.w = v3;
        *(float4*)(Cf + (size_t)row * N + colb) = of;
      }
    }
  }
}

// ---------------- per-head K2/Q2: out = relu(A_h * W_h^T + b_h) ----------------
__global__ __launch_bounds__(256) void k2q2_kernel(
    const unsigned short* __restrict__ kqv, const unsigned short* __restrict__ wk2,
    const unsigned short* __restrict__ wq2, const float* __restrict__ k2b,
    const float* __restrict__ q2b, unsigned short* __restrict__ kbuf,
    unsigned short* __restrict__ qbuf) {
  const int m0 = blockIdx.x * 64;
  const int h = blockIdx.y;
  const int which = blockIdx.z;
  const unsigned short* Ap = kqv + (which ? 1024 : 0) + h * 64;
  const unsigned short* Wp = (which ? wq2 : wk2) + h * 4096;
  const float* bias = (which ? q2b : k2b) + h * 64;
  unsigned short* out = (which ? qbuf : kbuf) + h * 64;
  const int lane = threadIdx.x & 63, wave = threadIdx.x >> 6;
  const int l16 = lane & 15, lhi = lane >> 4;
  const int mw = m0 + wave * 16;

  f32x4 acc[4] = {};
#pragma unroll
  for (int ks = 0; ks < 2; ks++) {
    bf16x8 a = *(const bf16x8*)(Ap + (size_t)(mw + l16) * 3072 + ks * 32 + (lhi << 3));
#pragma unroll
    for (int j = 0; j < 4; j++) {
      bf16x8 b = *(const bf16x8*)(Wp + (j * 16 + l16) * 64 + ks * 32 + (lhi << 3));
      acc[j] = __builtin_amdgcn_mfma_f32_16x16x32_bf16(a, b, acc[j], 0, 0, 0);
    }
  }
#pragma unroll
  for (int j = 0; j < 4; j++) {
    float bv = bias[j * 16 + l16];
#pragma unroll
    for (int r = 0; r < 4; r++) {
      int row = mw + (lhi << 2) + r;
      float v = fmaxf(acc[j][r] + bv, 0.f);
      out[(size_t)row * 1024 + j * 16 + l16] = f2b(v);
    }
  }
}

// ---------------- fused attention (future-masked, online softmax) ----------------
__global__ __launch_bounds__(256) void attn_kernel(
    const unsigned short* __restrict__ qbuf,  // [2048][1024]
    const unsigned short* __restrict__ kbuf,  // [2048][1024]
    const unsigned short* __restrict__ kqv,   // v at col 2048, stride 3072
    float* __restrict__ o32) {                // [2048][1024]
  constexpr int LD = 72;
  __shared__ __align__(16) unsigned short sK[64 * LD];
  __shared__ __align__(16) unsigned short sV[64 * LD];  // transposed: [d][t]
  __shared__ __align__(16) unsigned short sP[4 * 16 * LD];
  const int bx = blockIdx.x, h = blockIdx.y, b = blockIdx.z;
  const int tid = threadIdx.x, lane = tid & 63, wave = tid >> 6;
  const int l16 = lane & 15, lhi = lane >> 4;
  const int base = b * S_;

  const int qrow = bx * 64 + wave * 16 + l16;
  bf16x8 aq[2];
#pragma unroll
  for (int ks = 0; ks < 2; ks++)
    aq[ks] = *(const bf16x8*)(qbuf + (size_t)(base + qrow) * 1024 + h * 64 + ks * 32 + (lhi << 3));

  f32x4 oacc[4] = {};
  float mrun[4], lrun[4];
#pragma unroll
  for (int r = 0; r < 4; r++) { mrun[r] = -1e10f; lrun[r] = 0.f; }
  const int srow_base = bx * 64 + wave * 16 + (lhi << 2);

  for (int t0 = 0; t0 < S_; t0 += 64) {
    uint4 rk[2], rv[2];
#pragma unroll
    for (int r = 0; r < 2; r++) {
      int c = r * 256 + tid;
      int trow = c >> 3, c8 = (c & 7) << 3;
      rk[r] = *(const uint4*)(kbuf + (size_t)(base + t0 + trow) * 1024 + h * 64 + c8);
      rv[r] = *(const uint4*)(kqv + (size_t)(base + t0 + trow) * 3072 + 2048 + h * 64 + c8);
    }
    __syncthreads();
#pragma unroll
    for (int r = 0; r < 2; r++) {
      int c = r * 256 + tid;
      int trow = c >> 3, c8 = (c & 7) << 3;
      *(uint4*)(sK + trow * LD + c8) = rk[r];
      const unsigned short* ts = (const unsigned short*)&rv[r];
#pragma unroll
      for (int j = 0; j < 8; j++) sV[(c8 + j) * LD + trow] = ts[j];
    }
    __syncthreads();

    f32x4 sacc[4] = {};
#pragma unroll
    for (int ks = 0; ks < 2; ks++) {
#pragma unroll
      for (int nt = 0; nt < 4; nt++) {
        bf16x8 bk = *(const bf16x8*)(sK + (nt * 16 + l16) * LD + ks * 32 + (lhi << 3));
        sacc[nt] = __builtin_amdgcn_mfma_f32_16x16x32_bf16(aq[ks], bk, sacc[nt], 0, 0, 0);
      }
    }
    float p[4][4];
#pragma unroll
    for (int nt = 0; nt < 4; nt++) {
      int tcol = t0 + nt * 16 + l16;
#pragma unroll
      for (int r = 0; r < 4; r++) {
        float v = sacc[nt][r] * 0.125f;
        if (tcol <= srow_base + r) v = -1e10f;
        p[nt][r] = v;
      }
    }
#pragma unroll
    for (int r = 0; r < 4; r++) {
      float m = fmaxf(fmaxf(p[0][r], p[1][r]), fmaxf(p[2][r], p[3][r]));
#pragma unroll
      for (int off = 1; off < 16; off <<= 1) m = fmaxf(m, __shfl_xor(m, off, 16));
      float mnew = fmaxf(mrun[r], m);
      float alpha = __expf(mrun[r] - mnew);
      mrun[r] = mnew;
      float rs = 0.f;
#pragma unroll
      for (int nt = 0; nt < 4; nt++) {
        float e = __expf(p[nt][r] - mnew);
        p[nt][r] = e; rs += e;
      }
#pragma unroll
      for (int off = 1; off < 16; off <<= 1) rs += __shfl_xor(rs, off, 16);
      lrun[r] = lrun[r] * alpha + rs;
      oacc[0][r] *= alpha; oacc[1][r] *= alpha; oacc[2][r] *= alpha; oacc[3][r] *= alpha;
    }
    unsigned short* sPw = sP + wave * 16 * LD;
#pragma unroll
    for (int nt = 0; nt < 4; nt++)
#pragma unroll
      for (int r = 0; r < 4; r++)
        sPw[((lhi << 2) + r) * LD + nt * 16 + l16] = f2b(p[nt][r]);
#pragma unroll
    for (int ks = 0; ks < 2; ks++) {
      bf16x8 ap = *(const bf16x8*)(sPw + l16 * LD + ks * 32 + (lhi << 3));
#pragma unroll
      for (int nt = 0; nt < 4; nt++) {
        bf16x8 bv = *(const bf16x8*)(sV + (nt * 16 + l16) * LD + ks * 32 + (lhi << 3));
        oacc[nt] = __builtin_amdgcn_mfma_f32_16x16x32_bf16(ap, bv, oacc[nt], 0, 0, 0);
      }
    }
  }
#pragma unroll
  for (int nt = 0; nt < 4; nt++) {
#pragma unroll
    for (int r = 0; r < 4; r++) {
      int row = srow_base + r;
      o32[(size_t)(base + row) * 1024 + h * 64 + nt * 16 + l16] = oacc[nt][r] / lrun[r];
    }
  }
}

// ---------------- residual + LayerNorm -> bf16 ----------------
__global__ __launch_bounds__(256) void ln_kernel(
    const float* __restrict__ x32, const float* __restrict__ o32,
    const float* __restrict__ lnw, const float* __restrict__ lnb,
    unsigned short* __restrict__ yn) {
  __shared__ float red[8];
  const int row = blockIdx.x, tid = threadIdx.x;
  const int lane = tid & 63, wave = tid >> 6;
  const int e0 = tid * 4;
  float4 xv = *(const float4*)(x32 + (size_t)row * E_ + e0);
  float4 ov = *(const float4*)(o32 + (size_t)row * E_ + e0);
  float y0 = xv.x + ov.x, y1 = xv.y + ov.y, y2 = xv.z + ov.z, y3 = xv.w + ov.w;
  float s = y0 + y1 + y2 + y3;
  float sq = y0 * y0 + y1 * y1 + y2 * y2 + y3 * y3;
#pragma unroll
  for (int off = 32; off > 0; off >>= 1) {
    s += __shfl_xor(s, off, 64);
    sq += __shfl_xor(sq, off, 64);
  }
  if (lane == 0) { red[wave * 2] = s; red[wave * 2 + 1] = sq; }
  __syncthreads();
  float ts = red[0] + red[2] + red[4] + red[6];
  float tsq = red[1] + red[3] + red[5] + red[7];
  float mu = ts * (1.f / E_);
  float var = tsq * (1.f / E_) - mu * mu;
  float rstd = rsqrtf(var + 1e-5f);
  float4 gv = *(const float4*)(lnw + e0);
  float4 bv = *(const float4*)(lnb + e0);
  ushort4 o;
  o.x = f2b((y0 - mu) * rstd * gv.x + bv.x);
  o.y = f2b((y1 - mu) * rstd * gv.y + bv.y);
  o.z = f2b((y2 - mu) * rstd * gv.z + bv.z);
  o.w = f2b((y3 - mu) * rstd * gv.w + bv.w);
  *(ushort4*)(yn + (size_t)row * E_ + e0) = o;
}

// ---------------------------------------------------------------------------
extern "C" void kernel_launch(void* const* d_in, const int* in_sizes, int n_in,
                              void* d_out, int out_size, void* d_ws, size_t ws_size,
                              hipStream_t stream) {
  const int* tokens  = (const int*)d_in[0];
  const float* emb   = (const float*)d_in[1];
  const float* pe    = (const float*)d_in[2];
  const float* k1w   = (const float*)d_in[3];
  const float* k1b   = (const float*)d_in[4];
  const float* k2w   = (const float*)d_in[5];
  const float* k2b   = (const float*)d_in[6];
  const float* q1w   = (const float*)d_in[7];
  const float* q1b   = (const float*)d_in[8];
  const float* q2w   = (const float*)d_in[9];
  const float* q2b   = (const float*)d_in[10];
  const float* vw    = (const float*)d_in[11];
  const float* vb    = (const float*)d_in[12];
  const float* lnw   = (const float*)d_in[13];
  const float* lnb   = (const float*)d_in[14];
  const float* p1w   = (const float*)d_in[15];
  const float* p1b   = (const float*)d_in[16];
  const float* p2w   = (const float*)d_in[17];
  const float* p2b   = (const float*)d_in[18];
  const float* predw = (const float*)d_in[19];
  const float* predb = (const float*)d_in[20];
  float* out = (float*)d_out;

  // -------- workspace carve --------
  char* p = (char*)d_ws;
  auto alloc = [&](size_t bytes) -> char* {
    char* r = p; p += (bytes + 255) & ~(size_t)255; return r;
  };
  unsigned short* wcat  = (unsigned short*)alloc((size_t)L_ * 3072 * 1024 * 2);  // k1|q1|v weights
  unsigned short* wk2   = (unsigned short*)alloc((size_t)L_ * H_ * 64 * 64 * 2);
  unsigned short* wq2   = (unsigned short*)alloc((size_t)L_ * H_ * 64 * 64 * 2);
  unsigned short* wp1   = (unsigned short*)alloc((size_t)L_ * 1024 * 1024 * 2);
  unsigned short* wp2   = (unsigned short*)alloc((size_t)L_ * 1024 * 1024 * 2);
  unsigned short* wpred = (unsigned short*)alloc((size_t)V_ * 1024 * 2);
  float*          bcat  = (float*)alloc((size_t)L_ * 3072 * 4);
  float*          x32   = (float*)alloc((size_t)M_ * 1024 * 4);
  unsigned short* xb    = (unsigned short*)alloc((size_t)M_ * 1024 * 2);
  unsigned short* kqv   = (unsigned short*)alloc((size_t)M_ * 3072 * 2);
  unsigned short* kbuf  = (unsigned short*)alloc((size_t)M_ * 1024 * 2);
  unsigned short* qbuf  = (unsigned short*)alloc((size_t)M_ * 1024 * 2);
  float*          o32   = (float*)alloc((size_t)M_ * 1024 * 4);
  unsigned short* yn    = (unsigned short*)alloc((size_t)M_ * 1024 * 2);
  unsigned short* h1    = (unsigned short*)alloc((size_t)M_ * 1024 * 2);
  if ((size_t)(p - (char*)d_ws) > ws_size) return;

  // -------- weight conversion (fp32 -> bf16), every call (stateless) --------
  cvt_seg_kernel<<<8192, 256, 0, stream>>>(k1w, wcat, 1048576, 3145728, 0);
  cvt_seg_kernel<<<8192, 256, 0, stream>>>(q1w, wcat, 1048576, 3145728, 1048576);
  cvt_seg_kernel<<<8192, 256, 0, stream>>>(vw,  wcat, 1048576, 3145728, 2097152);
  cvt_kernel<<<512, 256, 0, stream>>>(k2w, wk2);
  cvt_kernel<<<512, 256, 0, stream>>>(q2w, wq2);
  cvt_kernel<<<8192, 256, 0, stream>>>(p1w, wp1);
  cvt_kernel<<<8192, 256, 0, stream>>>(p2w, wp2);
  cvt_kernel<<<32000, 256, 0, stream>>>(predw, wpred);
  biascat_kernel<<<96, 256, 0, stream>>>(k1b, q1b, vb, bcat);

  // -------- embedding --------
  embed_kernel<<<M_, 256, 0, stream>>>(tokens, emb, pe, x32, xb);

  // -------- layers --------
  for (int l = 0; l < L_; l++) {
    const unsigned short* wcat_l = wcat + (size_t)l * 3072 * 1024;
    const float* bcat_l = bcat + (size_t)l * 3072;
    const unsigned short* wk2_l = wk2 + (size_t)l * H_ * 64 * 64;
    const unsigned short* wq2_l = wq2 + (size_t)l * H_ * 64 * 64;
    const unsigned short* wp1_l = wp1 + (size_t)l * 1024 * 1024;
    const unsigned short* wp2_l = wp2 + (size_t)l * 1024 * 1024;

    // fused k1|q1|v projection: [2048,3072]; relu on cols<2048
    gemm97<128, 2, 1, 0><<<dim3(16, 24), 256, 0, stream>>>(
        xb, wcat_l, bcat_l, kqv, nullptr, 1024, 3072, 2048);
    k2q2_kernel<<<dim3(32, 16, 2), 256, 0, stream>>>(
        kqv, wk2_l, wq2_l, k2b + l * 1024, q2b + l * 1024, kbuf, qbuf);
    attn_kernel<<<dim3(16, 16, 2), 256, 0, stream>>>(qbuf, kbuf, kqv, o32);
    ln_kernel<<<M_, 256, 0, stream>>>(x32, o32, lnw + l * 1024, lnb + l * 1024, yn);
    gemm97<64, 1, 1, 0><<<dim3(32, 8), 256, 0, stream>>>(
        yn, wp1_l, p1b + l * 1024, h1, nullptr, 1024, 1024, 0);
    gemm97<64, 1, 1, 1><<<dim3(32, 8), 256, 0, stream>>>(
        h1, wp2_l, p2b + l * 1024, xb, x32, 1024, 1024, 0);
  }

  // -------- vocab projection --------
  gemm97<128, 0, 0, 1><<<dim3(16, 250), 256, 0, stream>>>(
      xb, wpred, predb, nullptr, out, 1024, V_, 0);
}

// Round 3
// 1496.055 us; speedup vs baseline: 1.4323x; 1.0390x over previous
//
#include <hip/hip_runtime.h>

// ---------------------------------------------------------------------------
// Transformer forward, MI355X gfx950. bf16 MFMA compute, fp32 accum/output.
//   activations: row = b*S + s (M = 2048 rows)
//   kqv buffer:  [2048][3072] bf16, cols = [k1(h,k) | q1(h,k) | v(h,d)]
//   vT buffer:   [32 bh][64 d][1024 t] bf16 (V transposed, written by kqv GEMM)
// GEMMs: m97 structure (global_load_lds w16, BK=32, 2 barriers/K-step),
// swapped-operand MFMA -> float4/ushort4 epilogue. Attention: barrier-free
// 2-wave blocks, direct-L2 K/V fragment loads, diagonal tile skip.
// ---------------------------------------------------------------------------

typedef __attribute__((ext_vector_type(8))) short bf16x8;
typedef __attribute__((ext_vector_type(4))) float f32x4;

#define L_ 8
#define S_ 1024
#define E_ 1024
#define B_ 2
#define H_ 16
#define V_ 32000
#define M_ 2048  // B*S

__device__ __forceinline__ unsigned short f2b(float f) {
  union { float f; unsigned int u; } v; v.f = f;
  unsigned int r = v.u + 0x7FFFu + ((v.u >> 16) & 1u);
  return (unsigned short)(r >> 16);
}

#define GLDS16(gptr, lptr)                                                            \
  __builtin_amdgcn_global_load_lds(                                                   \
      (const __attribute__((address_space(1))) unsigned int*)(gptr),                  \
      (__attribute__((address_space(3))) unsigned int*)(lptr), 16, 0, 0)

// ---------------- weight conversion kernels ----------------
__global__ void cvt_kernel(const float* __restrict__ src, unsigned short* __restrict__ dst) {
  size_t i = ((size_t)blockIdx.x * 256 + threadIdx.x) * 4;
  float4 v = *(const float4*)(src + i);
  unsigned short* d = dst + i;
  d[0] = f2b(v.x); d[1] = f2b(v.y); d[2] = f2b(v.z); d[3] = f2b(v.w);
}

__global__ void cvt_seg_kernel(const float* __restrict__ src, unsigned short* __restrict__ dst,
                               int perLayer, int dstStride, int dstOff) {
  size_t i = ((size_t)blockIdx.x * 256 + threadIdx.x) * 4;
  int l = (int)(i / perLayer);
  int off = (int)(i - (size_t)l * perLayer);
  float4 v = *(const float4*)(src + i);
  unsigned short* d = dst + (size_t)l * dstStride + dstOff + off;
  d[0] = f2b(v.x); d[1] = f2b(v.y); d[2] = f2b(v.z); d[3] = f2b(v.w);
}

__global__ void biascat_kernel(const float* __restrict__ k1b, const float* __restrict__ q1b,
                               const float* __restrict__ vb, float* __restrict__ bcat) {
  int i = blockIdx.x * 256 + threadIdx.x;  // 8*3072 exact
  int l = i / 3072, j = i - l * 3072;
  float v;
  if (j < 1024)      v = k1b[l * 1024 + j];
  else if (j < 2048) v = q1b[l * 1024 + j - 1024];
  else               v = vb [l * 1024 + j - 2048];
  bcat[i] = v;
}

// ---------------- embedding ----------------
__global__ void embed_kernel(const int* __restrict__ tokens, const float* __restrict__ emb,
                             const float* __restrict__ pe, float* __restrict__ x32,
                             unsigned short* __restrict__ xb) {
  int row = blockIdx.x;           // b*S + s
  int s = row & (S_ - 1);
  int e0 = threadIdx.x * 4;
  int tok = tokens[row];
  float4 ev = *(const float4*)(emb + (size_t)tok * E_ + e0);
  float4 pv = *(const float4*)(pe + (size_t)s * E_ + e0);
  float4 v; v.x = ev.x + pv.x; v.y = ev.y + pv.y; v.z = ev.z + pv.z; v.w = ev.w + pv.w;
  *(float4*)(x32 + (size_t)row * E_ + e0) = v;
  ushort4 o; o.x = f2b(v.x); o.y = f2b(v.y); o.z = f2b(v.z); o.w = f2b(v.w);
  *(ushort4*)(xb + (size_t)row * E_ + e0) = o;
}

// ---------------- m97-style GEMM: C = act(A * W^T + bias) ----------------
// A: [M][K] bf16, W: [N][K] bf16. BK=32. 4 waves in 2x2, wave = (BM/2)x(BN/2).
// RELU: 0 none, 1 all, 2 only cols < reluN. VT: also write transposed V panel.
template <int BM, int BN, int RELU, int OBF, int OF32, int VT>
__global__ __launch_bounds__(256) void gemm97(
    const unsigned short* __restrict__ A, const unsigned short* __restrict__ W,
    const float* __restrict__ bias, unsigned short* __restrict__ Cb,
    float* __restrict__ Cf, unsigned short* __restrict__ vTp,
    int K, int N, int reluN) {
  constexpr int AR = BM / 64;          // A glds issues per K-step
  constexpr int BR = BN / 64;          // B glds issues per K-step
  constexpr int FM = BM / 32;          // M frags per wave
  constexpr int FN = BN / 32;          // N frags per wave
  __shared__ __align__(16) unsigned short sA[BM * 32];
  __shared__ __align__(16) unsigned short sB[BN * 32];
  const int tid = threadIdx.x;
  const int lane = tid & 63, wave = tid >> 6;
  const int l16 = lane & 15, lhi = lane >> 4;

  // XCD-aware swizzle (grids here are %8==0; guard anyway)
  const int gx = gridDim.x, nwg = gx * gridDim.y;
  int o = blockIdx.y * gx + blockIdx.x;
  int wg = ((nwg & 7) == 0) ? ((o & 7) * (nwg >> 3) + (o >> 3)) : o;
  const int row0 = (wg % gx) * BM, col0 = (wg / gx) * BN;

  const int wm = (wave >> 1) * (BM / 2), wn = (wave & 1) * (BN / 2);

  const int srow = wave * 16 + (lane >> 2);   // 64 rows covered per issue
  const int scol = (lane & 3) * 8;

  f32x4 acc[FM][FN] = {};

  for (int k0 = 0; k0 < K; k0 += 32) {
#pragma unroll
    for (int r = 0; r < AR; r++)
      GLDS16(A + (size_t)(row0 + r * 64 + srow) * K + k0 + scol,
             sA + r * 2048 + wave * 512);
#pragma unroll
    for (int r = 0; r < BR; r++)
      GLDS16(W + (size_t)(col0 + r * 64 + srow) * K + k0 + scol,
             sB + r * 2048 + wave * 512);
    __syncthreads();

    bf16x8 af[FM], bf[FN];
#pragma unroll
    for (int i = 0; i < FM; i++)
      af[i] = *(const bf16x8*)(sA + (wm + i * 16 + l16) * 32 + lhi * 8);
#pragma unroll
    for (int j = 0; j < FN; j++)
      bf[j] = *(const bf16x8*)(sB + (wn + j * 16 + l16) * 32 + lhi * 8);
#pragma unroll
    for (int i = 0; i < FM; i++)
#pragma unroll
      for (int j = 0; j < FN; j++)
        acc[i][j] = __builtin_amdgcn_mfma_f32_16x16x32_bf16(bf[j], af[i], acc[i][j], 0, 0, 0);
    __syncthreads();
  }

#pragma unroll
  for (int j = 0; j < FN; j++) {
    const int colb = col0 + wn + j * 16 + lhi * 4;
    const float4 bv = *(const float4*)(bias + colb);
    const bool dorelu = (RELU == 1) || (RELU == 2 && colb < reluN);
#pragma unroll
    for (int i = 0; i < FM; i++) {
      const int row = row0 + wm + i * 16 + l16;
      float v0 = acc[i][j][0] + bv.x, v1 = acc[i][j][1] + bv.y;
      float v2 = acc[i][j][2] + bv.z, v3 = acc[i][j][3] + bv.w;
      if (dorelu) {
        v0 = fmaxf(v0, 0.f); v1 = fmaxf(v1, 0.f);
        v2 = fmaxf(v2, 0.f); v3 = fmaxf(v3, 0.f);
      }
      if (OBF) {
        ushort4 ob; ob.x = f2b(v0); ob.y = f2b(v1); ob.z = f2b(v2); ob.w = f2b(v3);
        *(ushort4*)(Cb + (size_t)row * N + colb) = ob;
      }
      if (OF32) {
        float4 of; of.x = v0; of.y = v1; of.z = v2; of.w = v3;
        *(float4*)(Cf + (size_t)row * N + colb) = of;
      }
      if (VT) {
        if (colb - lhi * 4 >= 2048) {  // whole fragment in v-range (uniform)
          const int hd0 = colb - 2048;
          const int bq = row >> 10, s = row & 1023;
          unsigned short* vr = vTp + ((size_t)(bq << 10) + hd0) * 1024 + s;
          vr[0] = f2b(v0); vr[1024] = f2b(v1); vr[2048] = f2b(v2); vr[3072] = f2b(v3);
        }
      }
    }
  }
}

// ---------------- per-head K2/Q2: out = relu(A_h * W_h^T + b_h) ----------------
__global__ __launch_bounds__(256) void k2q2_kernel(
    const unsigned short* __restrict__ kqv, const unsigned short* __restrict__ wk2,
    const unsigned short* __restrict__ wq2, const float* __restrict__ k2b,
    const float* __restrict__ q2b, unsigned short* __restrict__ kbuf,
    unsigned short* __restrict__ qbuf) {
  const int m0 = blockIdx.x * 64;
  const int h = blockIdx.y;
  const int which = blockIdx.z;
  const unsigned short* Ap = kqv + (which ? 1024 : 0) + h * 64;
  const unsigned short* Wp = (which ? wq2 : wk2) + h * 4096;
  const float* bias = (which ? q2b : k2b) + h * 64;
  unsigned short* out = (which ? qbuf : kbuf) + h * 64;
  const int lane = threadIdx.x & 63, wave = threadIdx.x >> 6;
  const int l16 = lane & 15, lhi = lane >> 4;
  const int mw = m0 + wave * 16;

  f32x4 acc[4] = {};
#pragma unroll
  for (int ks = 0; ks < 2; ks++) {
    bf16x8 a = *(const bf16x8*)(Ap + (size_t)(mw + l16) * 3072 + ks * 32 + (lhi << 3));
#pragma unroll
    for (int j = 0; j < 4; j++) {
      bf16x8 b = *(const bf16x8*)(Wp + (j * 16 + l16) * 64 + ks * 32 + (lhi << 3));
      acc[j] = __builtin_amdgcn_mfma_f32_16x16x32_bf16(a, b, acc[j], 0, 0, 0);
    }
  }
#pragma unroll
  for (int j = 0; j < 4; j++) {
    float bv = bias[j * 16 + l16];
#pragma unroll
    for (int r = 0; r < 4; r++) {
      int row = mw + (lhi << 2) + r;
      float v = fmaxf(acc[j][r] + bv, 0.f);
      out[(size_t)row * 1024 + j * 16 + l16] = f2b(v);
    }
  }
}

// ---------------- fused attention: barrier-free, direct-L2 K/V ----------------
// grid: 1024 blocks of 128 thr (2 waves). blockIdx = qt*32 + bh so all q-tiles
// of one (b,h) land on the same XCD (consecutive blocks round-robin XCDs).
// Mask is anti-causal (attend t > s): tiles entirely at/before the diagonal are
// fully masked; skipping them is bit-exact because a later real max wipes
// masked accumulation with alpha = expf(-1e10 - m_new) == 0.0f. The q-block
// containing row S-1 (qt==31) runs all tiles (row S-1 is uniform-softmax).
__global__ __launch_bounds__(128) void attn_kernel(
    const unsigned short* __restrict__ qbuf,  // [2048][1024]
    const unsigned short* __restrict__ kbuf,  // [2048][1024]
    const unsigned short* __restrict__ vT,    // [32][64][1024]
    float* __restrict__ o32) {                // [2048][1024]
  constexpr int LD = 72;
  __shared__ __align__(16) unsigned short sP[2 * 16 * LD];
  const int bid = blockIdx.x;
  const int bh = bid & 31, qt = bid >> 5;
  const int b = bh >> 4, h = bh & 15;
  const int tid = threadIdx.x, lane = tid & 63, w = tid >> 6;
  const int l16 = lane & 15, lhi = lane >> 4;
  const int base = b * S_;
  const int qrow = qt * 32 + w * 16 + l16;

  bf16x8 aq[2];
#pragma unroll
  for (int ks = 0; ks < 2; ks++)
    aq[ks] = *(const bf16x8*)(qbuf + (size_t)(base + qrow) * 1024 + h * 64 + ks * 32 + (lhi << 3));

  f32x4 oacc[4] = {};
  float mrun[4], lrun[4];
#pragma unroll
  for (int r = 0; r < 4; r++) { mrun[r] = -1e10f; lrun[r] = 0.f; }
  const int srow = qt * 32 + w * 16 + (lhi << 2);
  const int t0s = (qt == 31) ? 0 : ((qt >> 1) << 6);

  unsigned short* sPw = sP + w * 16 * LD;

  for (int t0 = t0s; t0 < S_; t0 += 64) {
    // S = Q K^T (K fragments straight from L2)
    f32x4 sacc[4] = {};
#pragma unroll
    for (int ks = 0; ks < 2; ks++) {
#pragma unroll
      for (int nt = 0; nt < 4; nt++) {
        bf16x8 bk = *(const bf16x8*)(kbuf + (size_t)(base + t0 + nt * 16 + l16) * 1024 +
                                     h * 64 + ks * 32 + (lhi << 3));
        sacc[nt] = __builtin_amdgcn_mfma_f32_16x16x32_bf16(aq[ks], bk, sacc[nt], 0, 0, 0);
      }
    }
    float p[4][4];
#pragma unroll
    for (int nt = 0; nt < 4; nt++) {
      int tcol = t0 + nt * 16 + l16;
#pragma unroll
      for (int r = 0; r < 4; r++) {
        float v = sacc[nt][r] * 0.125f;
        if (tcol <= srow + r) v = -1e10f;
        p[nt][r] = v;
      }
    }
#pragma unroll
    for (int r = 0; r < 4; r++) {
      float m = fmaxf(fmaxf(p[0][r], p[1][r]), fmaxf(p[2][r], p[3][r]));
#pragma unroll
      for (int off = 1; off < 16; off <<= 1) m = fmaxf(m, __shfl_xor(m, off, 16));
      float mnew = fmaxf(mrun[r], m);
      float alpha = __expf(mrun[r] - mnew);
      mrun[r] = mnew;
      float rs = 0.f;
#pragma unroll
      for (int nt = 0; nt < 4; nt++) {
        float e = __expf(p[nt][r] - mnew);
        p[nt][r] = e; rs += e;
      }
#pragma unroll
      for (int off = 1; off < 16; off <<= 1) rs += __shfl_xor(rs, off, 16);
      lrun[r] = lrun[r] * alpha + rs;
      oacc[0][r] *= alpha; oacc[1][r] *= alpha; oacc[2][r] *= alpha; oacc[3][r] *= alpha;
    }
    // P -> per-wave LDS (C-layout to A-layout transpose); no cross-wave use
#pragma unroll
    for (int nt = 0; nt < 4; nt++)
#pragma unroll
      for (int r = 0; r < 4; r++)
        sPw[((lhi << 2) + r) * LD + nt * 16 + l16] = f2b(p[nt][r]);
    // O += P V (V^T fragments straight from L2)
#pragma unroll
    for (int ks = 0; ks < 2; ks++) {
      bf16x8 ap = *(const bf16x8*)(sPw + l16 * LD + ks * 32 + (lhi << 3));
#pragma unroll
      for (int nt = 0; nt < 4; nt++) {
        bf16x8 bv = *(const bf16x8*)(vT + (size_t)(bh * 64 + nt * 16 + l16) * 1024 +
                                     t0 + ks * 32 + (lhi << 3));
        oacc[nt] = __builtin_amdgcn_mfma_f32_16x16x32_bf16(ap, bv, oacc[nt], 0, 0, 0);
      }
    }
  }
#pragma unroll
  for (int nt = 0; nt < 4; nt++) {
#pragma unroll
    for (int r = 0; r < 4; r++) {
      int row = srow + r;
      o32[(size_t)(base + row) * 1024 + h * 64 + nt * 16 + l16] = oacc[nt][r] / lrun[r];
    }
  }
}

// ---------------- residual + LayerNorm -> bf16 ----------------
__global__ __launch_bounds__(256) void ln_kernel(
    const float* __restrict__ x32, const float* __restrict__ o32,
    const float* __restrict__ lnw, const float* __restrict__ lnb,
    unsigned short* __restrict__ yn) {
  __shared__ float red[8];
  const int row = blockIdx.x, tid = threadIdx.x;
  const int lane = tid & 63, wave = tid >> 6;
  const int e0 = tid * 4;
  float4 xv = *(const float4*)(x32 + (size_t)row * E_ + e0);
  float4 ov = *(const float4*)(o32 + (size_t)row * E_ + e0);
  float y0 = xv.x + ov.x, y1 = xv.y + ov.y, y2 = xv.z + ov.z, y3 = xv.w + ov.w;
  float s = y0 + y1 + y2 + y3;
  float sq = y0 * y0 + y1 * y1 + y2 * y2 + y3 * y3;
#pragma unroll
  for (int off = 32; off > 0; off >>= 1) {
    s += __shfl_xor(s, off, 64);
    sq += __shfl_xor(sq, off, 64);
  }
  if (lane == 0) { red[wave * 2] = s; red[wave * 2 + 1] = sq; }
  __syncthreads();
  float ts = red[0] + red[2] + red[4] + red[6];
  float tsq = red[1] + red[3] + red[5] + red[7];
  float mu = ts * (1.f / E_);
  float var = tsq * (1.f / E_) - mu * mu;
  float rstd = rsqrtf(var + 1e-5f);
  float4 gv = *(const float4*)(lnw + e0);
  float4 bv = *(const float4*)(lnb + e0);
  ushort4 o;
  o.x = f2b((y0 - mu) * rstd * gv.x + bv.x);
  o.y = f2b((y1 - mu) * rstd * gv.y + bv.y);
  o.z = f2b((y2 - mu) * rstd * gv.z + bv.z);
  o.w = f2b((y3 - mu) * rstd * gv.w + bv.w);
  *(ushort4*)(yn + (size_t)row * E_ + e0) = o;
}

// ---------------------------------------------------------------------------
extern "C" void kernel_launch(void* const* d_in, const int* in_sizes, int n_in,
                              void* d_out, int out_size, void* d_ws, size_t ws_size,
                              hipStream_t stream) {
  const int* tokens  = (const int*)d_in[0];
  const float* emb   = (const float*)d_in[1];
  const float* pe    = (const float*)d_in[2];
  const float* k1w   = (const float*)d_in[3];
  const float* k1b   = (const float*)d_in[4];
  const float* k2w   = (const float*)d_in[5];
  const float* k2b   = (const float*)d_in[6];
  const float* q1w   = (const float*)d_in[7];
  const float* q1b   = (const float*)d_in[8];
  const float* q2w   = (const float*)d_in[9];
  const float* q2b   = (const float*)d_in[10];
  const float* vw    = (const float*)d_in[11];
  const float* vb    = (const float*)d_in[12];
  const float* lnw   = (const float*)d_in[13];
  const float* lnb   = (const float*)d_in[14];
  const float* p1w   = (const float*)d_in[15];
  const float* p1b   = (const float*)d_in[16];
  const float* p2w   = (const float*)d_in[17];
  const float* p2b   = (const float*)d_in[18];
  const float* predw = (const float*)d_in[19];
  const float* predb = (const float*)d_in[20];
  float* out = (float*)d_out;

  // -------- workspace carve --------
  char* p = (char*)d_ws;
  auto alloc = [&](size_t bytes) -> char* {
    char* r = p; p += (bytes + 255) & ~(size_t)255; return r;
  };
  unsigned short* wcat  = (unsigned short*)alloc((size_t)L_ * 3072 * 1024 * 2);
  unsigned short* wk2   = (unsigned short*)alloc((size_t)L_ * H_ * 64 * 64 * 2);
  unsigned short* wq2   = (unsigned short*)alloc((size_t)L_ * H_ * 64 * 64 * 2);
  unsigned short* wp1   = (unsigned short*)alloc((size_t)L_ * 1024 * 1024 * 2);
  unsigned short* wp2   = (unsigned short*)alloc((size_t)L_ * 1024 * 1024 * 2);
  unsigned short* wpred = (unsigned short*)alloc((size_t)V_ * 1024 * 2);
  float*          bcat  = (float*)alloc((size_t)L_ * 3072 * 4);
  float*          x32   = (float*)alloc((size_t)M_ * 1024 * 4);
  unsigned short* xb    = (unsigned short*)alloc((size_t)M_ * 1024 * 2);
  unsigned short* kqv   = (unsigned short*)alloc((size_t)M_ * 3072 * 2);
  unsigned short* kbuf  = (unsigned short*)alloc((size_t)M_ * 1024 * 2);
  unsigned short* qbuf  = (unsigned short*)alloc((size_t)M_ * 1024 * 2);
  unsigned short* vTb   = (unsigned short*)alloc((size_t)32 * 64 * 1024 * 2);
  float*          o32   = (float*)alloc((size_t)M_ * 1024 * 4);
  unsigned short* yn    = (unsigned short*)alloc((size_t)M_ * 1024 * 2);
  unsigned short* h1    = (unsigned short*)alloc((size_t)M_ * 1024 * 2);
  if ((size_t)(p - (char*)d_ws) > ws_size) return;

  // -------- weight conversion (fp32 -> bf16), every call (stateless) --------
  cvt_seg_kernel<<<8192, 256, 0, stream>>>(k1w, wcat, 1048576, 3145728, 0);
  cvt_seg_kernel<<<8192, 256, 0, stream>>>(q1w, wcat, 1048576, 3145728, 1048576);
  cvt_seg_kernel<<<8192, 256, 0, stream>>>(vw,  wcat, 1048576, 3145728, 2097152);
  cvt_kernel<<<512, 256, 0, stream>>>(k2w, wk2);
  cvt_kernel<<<512, 256, 0, stream>>>(q2w, wq2);
  cvt_kernel<<<8192, 256, 0, stream>>>(p1w, wp1);
  cvt_kernel<<<8192, 256, 0, stream>>>(p2w, wp2);
  cvt_kernel<<<32000, 256, 0, stream>>>(predw, wpred);
  biascat_kernel<<<96, 256, 0, stream>>>(k1b, q1b, vb, bcat);

  // -------- embedding --------
  embed_kernel<<<M_, 256, 0, stream>>>(tokens, emb, pe, x32, xb);

  // -------- layers --------
  for (int l = 0; l < L_; l++) {
    const unsigned short* wcat_l = wcat + (size_t)l * 3072 * 1024;
    const float* bcat_l = bcat + (size_t)l * 3072;
    const unsigned short* wk2_l = wk2 + (size_t)l * H_ * 64 * 64;
    const unsigned short* wq2_l = wq2 + (size_t)l * H_ * 64 * 64;
    const unsigned short* wp1_l = wp1 + (size_t)l * 1024 * 1024;
    const unsigned short* wp2_l = wp2 + (size_t)l * 1024 * 1024;

    // fused k1|q1|v projection; relu on cols<2048; writes vT for the v-range
    gemm97<128, 128, 2, 1, 0, 1><<<dim3(16, 24), 256, 0, stream>>>(
        xb, wcat_l, bcat_l, kqv, nullptr, vTb, 1024, 3072, 2048);
    k2q2_kernel<<<dim3(32, 16, 2), 256, 0, stream>>>(
        kqv, wk2_l, wq2_l, k2b + l * 1024, q2b + l * 1024, kbuf, qbuf);
    attn_kernel<<<1024, 128, 0, stream>>>(qbuf, kbuf, vTb, o32);
    ln_kernel<<<M_, 256, 0, stream>>>(x32, o32, lnw + l * 1024, lnb + l * 1024, yn);
    gemm97<64, 64, 1, 1, 0, 0><<<dim3(32, 16), 256, 0, stream>>>(
        yn, wp1_l, p1b + l * 1024, h1, nullptr, nullptr, 1024, 1024, 0);
    gemm97<64, 64, 1, 1, 1, 0><<<dim3(32, 16), 256, 0, stream>>>(
        h1, wp2_l, p2b + l * 1024, xb, x32, nullptr, 1024, 1024, 0);
  }

  // -------- vocab projection --------
  gemm97<128, 128, 0, 0, 1, 0><<<dim3(16, 250), 256, 0, stream>>>(
      xb, wpred, predb, nullptr, out, nullptr, 1024, V_, 0);
}